// Round 5
// baseline (1031.723 us; speedup 1.0000x reference)
//
#include <hip/hip_runtime.h>
#include <hip/hip_fp16.h>

#define S_LEN 2048
#define DHEAD 64
#define NBH   32      // B*H
#define NHEADS 16

typedef _Float16 half_t;
typedef half_t half8  __attribute__((ext_vector_type(8)));
typedef half_t half4v __attribute__((ext_vector_type(4)));
typedef __fp16 fp16x2 __attribute__((ext_vector_type(2)));   // cvt_pkrtz return type
typedef float  f32x16 __attribute__((ext_vector_type(16)));
typedef float  f32x4  __attribute__((ext_vector_type(4)));

#define QSCALE 0.18033688011112042f   // 0.125 * log2(e): fold 1/sqrt(64) and exp->exp2 into inputs

// ---------------------------------------------------------------------------
// Prep: qh = q*QSCALE (f16, [BH,S,D]); krh = k+r (f16, [BH,S,D]);
//       vt = V^T (f16, [BH,D,S]); c2 = (r_w_bias.k + r_bias.r)*QSCALE (f32, [BH,S])
// ---------------------------------------------------------------------------
__global__ __launch_bounds__(256) void prep_kernel(
    const float* __restrict__ q, const float* __restrict__ k,
    const float* __restrict__ v, const float* __restrict__ r,
    const float* __restrict__ r_bias, const float* __restrict__ r_w_bias,
    half_t* __restrict__ qh, half_t* __restrict__ krh,
    half_t* __restrict__ vt, float* __restrict__ c2)
{
    __shared__ float vtile[64][65];           // [d][s], +1 pad
    int blk = blockIdx.x;
    int st  = blk & 31;                       // S/64 = 32 tiles
    int bh  = blk >> 5;                       // 0..31
    int b = bh >> 4, h = bh & 15;
    int s0 = st * 64;
    int t = threadIdx.x;
    int dg = t & 15;                          // d-group: d = 4*dg..4*dg+3
    int rw = t >> 4;                          // 0..15
    const float4 ub = *(const float4*)(r_w_bias + h * 64 + 4 * dg);
    const float4 vb = *(const float4*)(r_bias   + h * 64 + 4 * dg);
    #pragma unroll
    for (int ps = 0; ps < 4; ++ps) {
        int row = ps * 16 + rw;
        size_t iidx = ((size_t)((b * S_LEN + s0 + row) * NHEADS + h)) * DHEAD + 4 * dg;
        float4 qv = *(const float4*)(q + iidx);
        float4 kv = *(const float4*)(k + iidx);
        float4 rv = *(const float4*)(r + iidx);
        float4 vv = *(const float4*)(v + iidx);
        size_t oidx = ((size_t)(bh * S_LEN + s0 + row)) * DHEAD + 4 * dg;
        half4v hq  = { (half_t)(qv.x * QSCALE), (half_t)(qv.y * QSCALE),
                       (half_t)(qv.z * QSCALE), (half_t)(qv.w * QSCALE) };
        half4v hkr = { (half_t)(kv.x + rv.x), (half_t)(kv.y + rv.y),
                       (half_t)(kv.z + rv.z), (half_t)(kv.w + rv.w) };
        *(half4v*)(qh  + oidx) = hq;
        *(half4v*)(krh + oidx) = hkr;
        vtile[4 * dg + 0][row] = vv.x;
        vtile[4 * dg + 1][row] = vv.y;
        vtile[4 * dg + 2][row] = vv.z;
        vtile[4 * dg + 3][row] = vv.w;
        float part = ub.x * kv.x + ub.y * kv.y + ub.z * kv.z + ub.w * kv.w
                   + vb.x * rv.x + vb.y * rv.y + vb.z * rv.z + vb.w * rv.w;
        #pragma unroll
        for (int mm = 1; mm <= 8; mm <<= 1) part += __shfl_xor(part, mm, 64);
        if (dg == 0) c2[(size_t)bh * S_LEN + s0 + row] = part * QSCALE;
    }
    __syncthreads();
    {   // write V^T: thread covers d = t>>2, 16 s-columns
        int d = t >> 2, j0 = (t & 3) * 16;
        const float* src = &vtile[d][j0];
        half8 h0, h1;
        #pragma unroll
        for (int e = 0; e < 8; ++e) { h0[e] = (half_t)src[e]; h1[e] = (half_t)src[8 + e]; }
        half_t* dst = vt + ((size_t)(bh * DHEAD + d)) * S_LEN + s0 + j0;
        *(half8*)(dst)     = h0;
        *(half8*)(dst + 8) = h1;
    }
}

// ---------------------------------------------------------------------------
// Attention. 256 blocks x 8 waves. Exact balance: SIMD s of every block hosts
// waves with qt = a and 63-a (a = (bb>>5)*4 + s)  => every SIMD machine-wide
// runs exactly 65 compute-tiles + 63 zero-tiles. Same-bh blocks share an XCD
// (bb&7) so per-XCD L2 working set = 4 heads of KR/V^T (2 MB).
// Swapped QK^T (mfma(KR,Q)): lane owns one q-row; max-free two-pass softmax.
// p_attn / zero-fill / out use nontemporal stores (never re-read).
// ---------------------------------------------------------------------------
__global__ __launch_bounds__(512) void attn_kernel(
    const half_t* __restrict__ qh, const half_t* __restrict__ krh,
    const half_t* __restrict__ vt, const float* __restrict__ c2,
    float* __restrict__ dout)
{
    int wid = threadIdx.x >> 6;               // 0..7
    int bb  = blockIdx.x;                     // 0..255
    int bh  = (bb & 7) * 4 + ((bb >> 3) & 3); // 4 heads per XCD
    int a   = (bb >> 5) * 4 + (wid & 3);      // 0..31
    int qt  = (wid < 4) ? a : (63 - a);       // SIMD-paired: a with 63-a
    int i0  = qt * 32;
    int lane = threadIdx.x & 63;
    int lo = lane & 31, hi = lane >> 5;
    int qrow = i0 + lo;

    const half_t* qp = qh  + ((size_t)(bh * S_LEN + i0)) * DHEAD;
    const half_t* kp = krh + ((size_t)bh * S_LEN) * DHEAD;
    const half_t* vp = vt  + ((size_t)bh * DHEAD) * S_LEN;
    const float*  cp = c2  + (size_t)bh * S_LEN;
    float* pout = dout + (size_t)NBH * S_LEN * DHEAD
                       + (size_t)bh * S_LEN * S_LEN
                       + (size_t)qrow * S_LEN + 4 * hi;
    float* oout = dout + ((size_t)(bh * S_LEN + i0)) * DHEAD;

    // zero-fill strictly-above-diagonal p tiles FIRST (stores overlap compute)
    {
        f32x4 zz = {};
        for (int tt = qt + 1; tt < 64; ++tt) {
            #pragma unroll
            for (int g = 0; g < 4; ++g)
                __builtin_nontemporal_store(zz, (f32x4*)(pout + tt * 32 + 8 * g));
        }
    }

    half8 qf[4];
    #pragma unroll
    for (int ds = 0; ds < 4; ++ds)
        qf[ds] = *(const half8*)(qp + lo * DHEAD + ds * 16 + hi * 8);

    auto loadK = [&](half8* kf, int t) {
        const half_t* base = kp + (size_t)(t * 32 + lo) * DHEAD + hi * 8;
        #pragma unroll
        for (int ds = 0; ds < 4; ++ds)
            kf[ds] = *(const half8*)(base + ds * 16);
    };
    auto loadV = [&](half8* vv, int t) {
        const half_t* r0 = vp + (size_t)lo * S_LEN + t * 32 + hi * 8;         // d = lo
        const half_t* r1 = vp + (size_t)(lo + 32) * S_LEN + t * 32 + hi * 8;  // d = lo+32
        vv[0] = *(const half8*)(r0);
        vv[1] = *(const half8*)(r0 + 16);
        vv[2] = *(const half8*)(r1);
        vv[3] = *(const half8*)(r1 + 16);
    };
    auto scoreT = [&](const half8* kf) {
        f32x16 acc = {};
        #pragma unroll
        for (int ds = 0; ds < 4; ++ds)
            acc = __builtin_amdgcn_mfma_f32_32x32x16_f16(kf[ds], qf[ds], acc, 0, 0, 0);
        return acc;
    };

    // ---------------- pass 1: Z = sum exp2(s) ----------------
    float Zs = 0.f;
    auto zTile = [&](int t, const half8* kf) {
        f32x16 acc = scoreT(kf);
        int jb = t * 32;
        float zs = 0.f;
        #pragma unroll
        for (int g = 0; g < 4; ++g) {
            f32x4 cv = *(const f32x4*)(cp + jb + 8 * g + 4 * hi);
            #pragma unroll
            for (int e = 0; e < 4; ++e) {
                float ev = exp2f(acc[4 * g + e] + cv[e]);
                if (t == qt) {
                    int j = jb + e + 8 * g + 4 * hi;
                    if (j > qrow) ev = 0.f;
                }
                zs += ev;
            }
        }
        Zs += zs;
    };
    {
        half8 kfA[4], kfB[4];
        loadK(kfA, 0);
        int t = 0;
        while (true) {
            if (t < qt) loadK(kfB, t + 1);
            zTile(t, kfA);
            if (++t > qt) break;
            if (t < qt) loadK(kfA, t + 1);
            zTile(t, kfB);
            if (++t > qt) break;
        }
    }
    float Zrow = Zs + __shfl_xor(Zs, 32, 64);
    float L = log2f(Zrow);                    // p = exp2(s - L)

    // ---------------- pass 2: recompute, write p, PV ----------------
    f32x16 oa0 = {}, oa1 = {};
    auto pvTile = [&](int t, const half8* kf, const half8* vv) {
        f32x16 acc = scoreT(kf);
        int jb = t * 32;
        float p[16];
        #pragma unroll
        for (int g = 0; g < 4; ++g) {
            f32x4 cv = *(const f32x4*)(cp + jb + 8 * g + 4 * hi);
            #pragma unroll
            for (int e = 0; e < 4; ++e)
                p[4 * g + e] = exp2f(acc[4 * g + e] + cv[e] - L);
        }
        if (t == qt) {
            #pragma unroll
            for (int xx = 0; xx < 16; ++xx) {
                int j = jb + (xx & 3) + 8 * (xx >> 2) + 4 * hi;
                if (j > qrow) p[xx] = 0.f;
            }
        }
        #pragma unroll
        for (int g = 0; g < 4; ++g) {
            f32x4 st4 = { p[4 * g], p[4 * g + 1], p[4 * g + 2], p[4 * g + 3] };
            __builtin_nontemporal_store(st4, (f32x4*)(pout + jb + 8 * g));
        }
        // pack p -> f16 dwords (pkrtz); exchange halves to build PV A-fragments
        unsigned int wds[8];
        #pragma unroll
        for (int g2 = 0; g2 < 8; ++g2) {
            union { fp16x2 h; unsigned int u; } pk;
            pk.h = __builtin_amdgcn_cvt_pkrtz(p[2 * g2], p[2 * g2 + 1]);
            wds[g2] = pk.u;
        }
        unsigned int pw[8];
        #pragma unroll
        for (int g2 = 0; g2 < 8; ++g2) pw[g2] = __shfl_xor(wds[g2], 32, 64);
        union { unsigned int uu[4]; half8 h; } pa0, pa1;
        pa0.uu[0] = hi ? pw[2]  : wds[0];
        pa0.uu[1] = hi ? pw[3]  : wds[1];
        pa0.uu[2] = hi ? wds[2] : pw[0];
        pa0.uu[3] = hi ? wds[3] : pw[1];
        pa1.uu[0] = hi ? pw[6]  : wds[4];
        pa1.uu[1] = hi ? pw[7]  : wds[5];
        pa1.uu[2] = hi ? wds[6] : pw[4];
        pa1.uu[3] = hi ? wds[7] : pw[5];
        oa0 = __builtin_amdgcn_mfma_f32_32x32x16_f16(pa0.h, vv[0], oa0, 0, 0, 0);
        oa0 = __builtin_amdgcn_mfma_f32_32x32x16_f16(pa1.h, vv[1], oa0, 0, 0, 0);
        oa1 = __builtin_amdgcn_mfma_f32_32x32x16_f16(pa0.h, vv[2], oa1, 0, 0, 0);
        oa1 = __builtin_amdgcn_mfma_f32_32x32x16_f16(pa1.h, vv[3], oa1, 0, 0, 0);
    };
    {
        half8 kfA[4], kfB[4], vA[4], vB[4];
        loadK(kfA, 0); loadV(vA, 0);
        int t = 0;
        while (true) {
            if (t < qt) { loadK(kfB, t + 1); loadV(vB, t + 1); }
            pvTile(t, kfA, vA);
            if (++t > qt) break;
            if (t < qt) { loadK(kfA, t + 1); loadV(vA, t + 1); }
            pvTile(t, kfB, vB);
            if (++t > qt) break;
        }
    }

    // write out[b,h,q,d]
    #pragma unroll
    for (int xx = 0; xx < 16; ++xx) {
        int row = (xx & 3) + 8 * (xx >> 2) + 4 * hi;
        __builtin_nontemporal_store(oa0[xx], oout + (size_t)row * DHEAD + lo);
        __builtin_nontemporal_store(oa1[xx], oout + (size_t)row * DHEAD + 32 + lo);
    }
}

// ---------------------------------------------------------------------------
extern "C" void kernel_launch(void* const* d_in, const int* in_sizes, int n_in,
                              void* d_out, int out_size, void* d_ws, size_t ws_size,
                              hipStream_t stream)
{
    const float* q   = (const float*)d_in[0];
    const float* k   = (const float*)d_in[1];
    const float* v   = (const float*)d_in[2];
    const float* r   = (const float*)d_in[3];
    const float* rb  = (const float*)d_in[4];   // r_bias
    const float* rwb = (const float*)d_in[5];   // r_w_bias
    // d_in[6] = mask (causal tril) — computed analytically, not read
    float* out = (float*)d_out;

    char* ws = (char*)d_ws;                     // needs 24.25 MB
    half_t* qh  = (half_t*)(ws);
    half_t* krh = (half_t*)(ws + (size_t) 8 * 1024 * 1024);
    half_t* vtp = (half_t*)(ws + (size_t)16 * 1024 * 1024);
    float*  c2  = (float*) (ws + (size_t)24 * 1024 * 1024);

    hipLaunchKernelGGL(prep_kernel, dim3(1024), dim3(256), 0, stream,
                       q, k, v, r, rb, rwb, qh, krh, vtp, c2);
    hipLaunchKernelGGL(attn_kernel, dim3(256), dim3(512), 0, stream,
                       qh, krh, vtp, c2, out);
}

// Round 7
// 706.942 us; speedup vs baseline: 1.4594x; 1.4594x over previous
//
#include <hip/hip_runtime.h>
#include <hip/hip_fp16.h>

#define S_LEN 2048
#define DHEAD 64
#define NBH   32      // B*H
#define NHEADS 16

typedef _Float16 half_t;
typedef half_t half8  __attribute__((ext_vector_type(8)));
typedef half_t half4v __attribute__((ext_vector_type(4)));
typedef __fp16 fp16x2 __attribute__((ext_vector_type(2)));   // cvt_pkrtz return type
typedef float  f32x16 __attribute__((ext_vector_type(16)));
typedef float  f32x4  __attribute__((ext_vector_type(4)));

#define QSCALE 0.18033688011112042f   // 0.125 * log2(e): fold 1/sqrt(64) and exp->exp2 into inputs

// ---------------------------------------------------------------------------
// Prep: qh = q*QSCALE (f16, [BH,S,D]); krh = k+r (f16, [BH,S,D]);
//       vt = V^T (f16, [BH,D,S]); c2 = (r_w_bias.k + r_bias.r)*QSCALE (f32, [BH,S])
// ---------------------------------------------------------------------------
__global__ __launch_bounds__(256) void prep_kernel(
    const float* __restrict__ q, const float* __restrict__ k,
    const float* __restrict__ v, const float* __restrict__ r,
    const float* __restrict__ r_bias, const float* __restrict__ r_w_bias,
    half_t* __restrict__ qh, half_t* __restrict__ krh,
    half_t* __restrict__ vt, float* __restrict__ c2)
{
    __shared__ float vtile[64][65];           // [d][s], +1 pad
    int blk = blockIdx.x;
    int st  = blk & 31;                       // S/64 = 32 tiles
    int bh  = blk >> 5;                       // 0..31
    int b = bh >> 4, h = bh & 15;
    int s0 = st * 64;
    int t = threadIdx.x;
    int dg = t & 15;                          // d-group: d = 4*dg..4*dg+3
    int rw = t >> 4;                          // 0..15
    const float4 ub = *(const float4*)(r_w_bias + h * 64 + 4 * dg);
    const float4 vb = *(const float4*)(r_bias   + h * 64 + 4 * dg);
    #pragma unroll
    for (int ps = 0; ps < 4; ++ps) {
        int row = ps * 16 + rw;
        size_t iidx = ((size_t)((b * S_LEN + s0 + row) * NHEADS + h)) * DHEAD + 4 * dg;
        float4 qv = *(const float4*)(q + iidx);
        float4 kv = *(const float4*)(k + iidx);
        float4 rv = *(const float4*)(r + iidx);
        float4 vv = *(const float4*)(v + iidx);
        size_t oidx = ((size_t)(bh * S_LEN + s0 + row)) * DHEAD + 4 * dg;
        half4v hq  = { (half_t)(qv.x * QSCALE), (half_t)(qv.y * QSCALE),
                       (half_t)(qv.z * QSCALE), (half_t)(qv.w * QSCALE) };
        half4v hkr = { (half_t)(kv.x + rv.x), (half_t)(kv.y + rv.y),
                       (half_t)(kv.z + rv.z), (half_t)(kv.w + rv.w) };
        *(half4v*)(qh  + oidx) = hq;
        *(half4v*)(krh + oidx) = hkr;
        vtile[4 * dg + 0][row] = vv.x;
        vtile[4 * dg + 1][row] = vv.y;
        vtile[4 * dg + 2][row] = vv.z;
        vtile[4 * dg + 3][row] = vv.w;
        float part = ub.x * kv.x + ub.y * kv.y + ub.z * kv.z + ub.w * kv.w
                   + vb.x * rv.x + vb.y * rv.y + vb.z * rv.z + vb.w * rv.w;
        #pragma unroll
        for (int mm = 1; mm <= 8; mm <<= 1) part += __shfl_xor(part, mm, 64);
        if (dg == 0) c2[(size_t)bh * S_LEN + s0 + row] = part * QSCALE;
    }
    __syncthreads();
    {   // write V^T: thread covers d = t>>2, 16 s-columns
        int d = t >> 2, j0 = (t & 3) * 16;
        const float* src = &vtile[d][j0];
        half8 h0, h1;
        #pragma unroll
        for (int e = 0; e < 8; ++e) { h0[e] = (half_t)src[e]; h1[e] = (half_t)src[8 + e]; }
        half_t* dst = vt + ((size_t)(bh * DHEAD + d)) * S_LEN + s0 + j0;
        *(half8*)(dst)     = h0;
        *(half8*)(dst + 8) = h1;
    }
}

// ---------------------------------------------------------------------------
// Attention. ONE BLOCK (4 waves) PER Q-TILE: 2048 blocks x 256 threads.
// The 4 waves split the j-tile range (stride 4) and combine via LDS:
//   pass 1: per-lane partial Z -> zl[4][64] -> every lane sums 8 values.
//   pass 2: per-wave partial PV accumulators -> staged f32x4 LDS tree.
// 8 blocks/CU queued -> scheduler backfills the causal-triangle imbalance;
// ~4 waves/SIMD resident hides the per-tile serial chain (the round-5
// bottleneck: 2 waves/SIMD, all pipes <10% busy).
// Swapped QK^T (mfma(KR,Q)): lane owns one q-row; max-free two-pass softmax.
// Cached (NOT nontemporal) stores: L2 merges the 32B row-chunks (round-5's
// nontemporal hint caused 1.7x write amplification, 917 vs 552 MB).
// ---------------------------------------------------------------------------
__global__ __launch_bounds__(256) void attn_kernel(
    const half_t* __restrict__ qh, const half_t* __restrict__ krh,
    const half_t* __restrict__ vt, const float* __restrict__ c2,
    float* __restrict__ dout)
{
    __shared__ float zl[4][64];
    __shared__ f32x4 pvred[2][8][64];         // [region][chunk][lane] — conflict-free

    int bb  = blockIdx.x;                     // 0..2047
    int bh  = (bb & 7) * 4 + ((bb >> 3) & 3); // 4 heads per XCD
    int qt  = 63 - (bb >> 5);                 // heavy q-tiles dispatched first
    int i0  = qt * 32;
    int w    = threadIdx.x >> 6;              // wave 0..3: handles j-tiles w, w+4, ...
    int lane = threadIdx.x & 63;
    int lo = lane & 31, hi = lane >> 5;
    int qrow = i0 + lo;

    const half_t* qp = qh  + ((size_t)(bh * S_LEN + i0)) * DHEAD;
    const half_t* kp = krh + ((size_t)bh * S_LEN) * DHEAD;
    const half_t* vp = vt  + ((size_t)bh * DHEAD) * S_LEN;
    const float*  cp = c2  + (size_t)bh * S_LEN;
    float* pout = dout + (size_t)NBH * S_LEN * DHEAD
                       + (size_t)bh * S_LEN * S_LEN
                       + (size_t)qrow * S_LEN + 4 * hi;
    float* oout = dout + ((size_t)(bh * S_LEN + i0)) * DHEAD;

    // zero-fill strictly-above-diagonal p tiles (split across waves)
    {
        f32x4 zz = {};
        for (int tt = qt + 1 + w; tt < 64; tt += 4) {
            #pragma unroll
            for (int g = 0; g < 4; ++g)
                *(f32x4*)(pout + tt * 32 + 8 * g) = zz;
        }
    }

    half8 qf[4];
    #pragma unroll
    for (int ds = 0; ds < 4; ++ds)
        qf[ds] = *(const half8*)(qp + lo * DHEAD + ds * 16 + hi * 8);

    auto loadK = [&](half8* kf, int t) {
        const half_t* base = kp + (size_t)(t * 32 + lo) * DHEAD + hi * 8;
        #pragma unroll
        for (int ds = 0; ds < 4; ++ds)
            kf[ds] = *(const half8*)(base + ds * 16);
    };
    auto loadV = [&](half8* vv, int t) {
        const half_t* r0 = vp + (size_t)lo * S_LEN + t * 32 + hi * 8;         // d = lo
        const half_t* r1 = vp + (size_t)(lo + 32) * S_LEN + t * 32 + hi * 8;  // d = lo+32
        vv[0] = *(const half8*)(r0);
        vv[1] = *(const half8*)(r0 + 16);
        vv[2] = *(const half8*)(r1);
        vv[3] = *(const half8*)(r1 + 16);
    };
    auto scoreT = [&](const half8* kf) {
        f32x16 acc = {};
        #pragma unroll
        for (int ds = 0; ds < 4; ++ds)
            acc = __builtin_amdgcn_mfma_f32_32x32x16_f16(kf[ds], qf[ds], acc, 0, 0, 0);
        return acc;
    };

    // ---------------- pass 1: partial Z = sum exp2(s) over this wave's tiles ----
    float Zs = 0.f;
    auto zTile = [&](int t, const half8* kf) {
        f32x16 acc = scoreT(kf);
        int jb = t * 32;
        float zs = 0.f;
        #pragma unroll
        for (int g = 0; g < 4; ++g) {
            f32x4 cv = *(const f32x4*)(cp + jb + 8 * g + 4 * hi);
            #pragma unroll
            for (int e = 0; e < 4; ++e) {
                float ev = exp2f(acc[4 * g + e] + cv[e]);
                if (t == qt) {
                    int j = jb + e + 8 * g + 4 * hi;
                    if (j > qrow) ev = 0.f;
                }
                zs += ev;
            }
        }
        Zs += zs;
    };
    {
        half8 kfA[4], kfB[4];
        int t = w;
        if (t <= qt) loadK(kfA, t);
        while (t <= qt) {
            if (t + 4 <= qt) loadK(kfB, t + 4);
            zTile(t, kfA);
            t += 4;
            if (t > qt) break;
            if (t + 4 <= qt) loadK(kfA, t + 4);
            zTile(t, kfB);
            t += 4;
        }
    }
    zl[w][lane] = Zs;
    __syncthreads();
    float Zrow = 0.f;
    #pragma unroll
    for (int w2 = 0; w2 < 4; ++w2) Zrow += zl[w2][lo] + zl[w2][lo + 32];
    float L = log2f(Zrow);                    // p = exp2(s - L)

    // ---------------- pass 2: recompute, write p, partial PV ----------------
    f32x16 oa0 = {}, oa1 = {};
    auto pvTile = [&](int t, const half8* kf, const half8* vv) {
        f32x16 acc = scoreT(kf);
        int jb = t * 32;
        float p[16];
        #pragma unroll
        for (int g = 0; g < 4; ++g) {
            f32x4 cv = *(const f32x4*)(cp + jb + 8 * g + 4 * hi);
            #pragma unroll
            for (int e = 0; e < 4; ++e)
                p[4 * g + e] = exp2f(acc[4 * g + e] + cv[e] - L);
        }
        if (t == qt) {
            #pragma unroll
            for (int xx = 0; xx < 16; ++xx) {
                int j = jb + (xx & 3) + 8 * (xx >> 2) + 4 * hi;
                if (j > qrow) p[xx] = 0.f;
            }
        }
        #pragma unroll
        for (int g = 0; g < 4; ++g) {
            f32x4 st4 = { p[4 * g], p[4 * g + 1], p[4 * g + 2], p[4 * g + 3] };
            *(f32x4*)(pout + jb + 8 * g) = st4;
        }
        // pack p -> f16 dwords (pkrtz); exchange halves to build PV A-fragments
        unsigned int wds[8];
        #pragma unroll
        for (int g2 = 0; g2 < 8; ++g2) {
            union { fp16x2 h; unsigned int u; } pk;
            pk.h = __builtin_amdgcn_cvt_pkrtz(p[2 * g2], p[2 * g2 + 1]);
            wds[g2] = pk.u;
        }
        unsigned int pw[8];
        #pragma unroll
        for (int g2 = 0; g2 < 8; ++g2) pw[g2] = __shfl_xor(wds[g2], 32, 64);
        union { unsigned int uu[4]; half8 h; } pa0, pa1;
        pa0.uu[0] = hi ? pw[2]  : wds[0];
        pa0.uu[1] = hi ? pw[3]  : wds[1];
        pa0.uu[2] = hi ? wds[2] : pw[0];
        pa0.uu[3] = hi ? wds[3] : pw[1];
        pa1.uu[0] = hi ? pw[6]  : wds[4];
        pa1.uu[1] = hi ? pw[7]  : wds[5];
        pa1.uu[2] = hi ? wds[6] : pw[4];
        pa1.uu[3] = hi ? wds[7] : pw[5];
        oa0 = __builtin_amdgcn_mfma_f32_32x32x16_f16(pa0.h, vv[0], oa0, 0, 0, 0);
        oa0 = __builtin_amdgcn_mfma_f32_32x32x16_f16(pa1.h, vv[1], oa0, 0, 0, 0);
        oa1 = __builtin_amdgcn_mfma_f32_32x32x16_f16(pa0.h, vv[2], oa1, 0, 0, 0);
        oa1 = __builtin_amdgcn_mfma_f32_32x32x16_f16(pa1.h, vv[3], oa1, 0, 0, 0);
    };
    {
        half8 kfA[4], kfB[4], vA[4], vB[4];
        int t = w;
        if (t <= qt) { loadK(kfA, t); loadV(vA, t); }
        while (t <= qt) {
            if (t + 4 <= qt) { loadK(kfB, t + 4); loadV(vB, t + 4); }
            pvTile(t, kfA, vA);
            t += 4;
            if (t > qt) break;
            if (t + 4 <= qt) { loadK(kfA, t + 4); loadV(vA, t + 4); }
            pvTile(t, kfB, vB);
            t += 4;
        }
    }

    // ---------------- block-combine partial PV and write out ----------------
    __syncthreads();          // zl reads done; pvred regions free
    if (w >= 2) {
        #pragma unroll
        for (int j = 0; j < 4; ++j) {
            f32x4 c0 = { oa0[4*j], oa0[4*j+1], oa0[4*j+2], oa0[4*j+3] };
            f32x4 c1 = { oa1[4*j], oa1[4*j+1], oa1[4*j+2], oa1[4*j+3] };
            pvred[w - 2][j][lane]     = c0;
            pvred[w - 2][j + 4][lane] = c1;
        }
    }
    __syncthreads();
    if (w < 2) {
        #pragma unroll
        for (int j = 0; j < 4; ++j) {
            f32x4 c0 = pvred[w][j][lane];
            f32x4 c1 = pvred[w][j + 4][lane];
            #pragma unroll
            for (int e = 0; e < 4; ++e) { oa0[4*j+e] += c0[e]; oa1[4*j+e] += c1[e]; }
        }
    }
    __syncthreads();
    if (w == 1) {
        #pragma unroll
        for (int j = 0; j < 4; ++j) {
            f32x4 c0 = { oa0[4*j], oa0[4*j+1], oa0[4*j+2], oa0[4*j+3] };
            f32x4 c1 = { oa1[4*j], oa1[4*j+1], oa1[4*j+2], oa1[4*j+3] };
            pvred[0][j][lane]     = c0;
            pvred[0][j + 4][lane] = c1;
        }
    }
    __syncthreads();
    if (w == 0) {
        #pragma unroll
        for (int j = 0; j < 4; ++j) {
            f32x4 c0 = pvred[0][j][lane];
            f32x4 c1 = pvred[0][j + 4][lane];
            #pragma unroll
            for (int e = 0; e < 4; ++e) { oa0[4*j+e] += c0[e]; oa1[4*j+e] += c1[e]; }
        }
        #pragma unroll
        for (int xx = 0; xx < 16; ++xx) {
            int row = (xx & 3) + 8 * (xx >> 2) + 4 * hi;
            oout[(size_t)row * DHEAD + lo]      = oa0[xx];
            oout[(size_t)row * DHEAD + 32 + lo] = oa1[xx];
        }
    }
}

// ---------------------------------------------------------------------------
extern "C" void kernel_launch(void* const* d_in, const int* in_sizes, int n_in,
                              void* d_out, int out_size, void* d_ws, size_t ws_size,
                              hipStream_t stream)
{
    const float* q   = (const float*)d_in[0];
    const float* k   = (const float*)d_in[1];
    const float* v   = (const float*)d_in[2];
    const float* r   = (const float*)d_in[3];
    const float* rb  = (const float*)d_in[4];   // r_bias
    const float* rwb = (const float*)d_in[5];   // r_w_bias
    // d_in[6] = mask (causal tril) — computed analytically, not read
    float* out = (float*)d_out;

    char* ws = (char*)d_ws;                     // needs 24.25 MB
    half_t* qh  = (half_t*)(ws);
    half_t* krh = (half_t*)(ws + (size_t) 8 * 1024 * 1024);
    half_t* vtp = (half_t*)(ws + (size_t)16 * 1024 * 1024);
    float*  c2  = (float*) (ws + (size_t)24 * 1024 * 1024);

    hipLaunchKernelGGL(prep_kernel, dim3(1024), dim3(256), 0, stream,
                       q, k, v, r, rb, rwb, qh, krh, vtp, c2);
    hipLaunchKernelGGL(attn_kernel, dim3(2048), dim3(256), 0, stream,
                       qh, krh, vtp, c2, out);
}